// Round 1
// baseline (1201.688 us; speedup 1.0000x reference)
//
#include <hip/hip_runtime.h>

// Problem constants (from reference): U=100000 users, I=50000 items, D=64.
// Output layout (flat, concatenated): [user_emb1 (U*D) | item_emb1 (I*D) |
// user_emb2 (U*D) | item_emb2 (I*D)].  user_emb1||item_emb1 == all_emb1 flat,
// so the graph SpMM scatters directly into out[0 : N*D].

#define DDIM 64
constexpr int U_CNT = 100000;
constexpr int I_CNT = 50000;
constexpr int N_CNT = U_CNT + I_CNT;  // 150000

// Graph SpMM: gather from concat(user_emb, item_emb) without materializing it.
// One wave per edge, lane = feature dim (D == wavefront size == 64).
__global__ void spmm_graph_kernel(const int* __restrict__ rows,
                                  const int* __restrict__ cols,
                                  const float* __restrict__ vals,
                                  const float* __restrict__ user_emb,
                                  const float* __restrict__ item_emb,
                                  float* __restrict__ out, int E) {
    long long idx = (long long)blockIdx.x * blockDim.x + threadIdx.x;
    int e = (int)(idx >> 6);
    int d = (int)(idx & 63);
    if (e >= E) return;
    int r = rows[e];
    int c = cols[e];
    float v = vals[e];
    float x = (c < U_CNT) ? user_emb[(long long)c * DDIM + d]
                          : item_emb[(long long)(c - U_CNT) * DDIM + d];
    atomicAdd(&out[(long long)r * DDIM + d], v * x);
}

// Plain SpMM: y[r] += v * emb[c], scatter into `out` (already offset by caller).
__global__ void spmm_plain_kernel(const int* __restrict__ rows,
                                  const int* __restrict__ cols,
                                  const float* __restrict__ vals,
                                  const float* __restrict__ emb,
                                  float* __restrict__ out, int E) {
    long long idx = (long long)blockIdx.x * blockDim.x + threadIdx.x;
    int e = (int)(idx >> 6);
    int d = (int)(idx & 63);
    if (e >= E) return;
    int r = rows[e];
    int c = cols[e];
    float v = vals[e];
    float x = emb[(long long)c * DDIM + d];
    atomicAdd(&out[(long long)r * DDIM + d], v * x);
}

extern "C" void kernel_launch(void* const* d_in, const int* in_sizes, int n_in,
                              void* d_out, int out_size, void* d_ws, size_t ws_size,
                              hipStream_t stream) {
    const float* user_emb = (const float*)d_in[0];
    const float* item_emb = (const float*)d_in[1];
    const int*   g_rows   = (const int*)d_in[2];
    const int*   g_cols   = (const int*)d_in[3];
    const float* g_vals   = (const float*)d_in[4];
    const int*   u_rows   = (const int*)d_in[5];
    const int*   u_cols   = (const int*)d_in[6];
    const float* u_vals   = (const float*)d_in[7];
    const int*   i_rows   = (const int*)d_in[8];
    const int*   i_cols   = (const int*)d_in[9];
    const float* i_vals   = (const float*)d_in[10];
    float* out = (float*)d_out;

    const int EG = in_sizes[2];
    const int EU = in_sizes[5];
    const int EI = in_sizes[8];

    // Harness poisons d_out with 0xAA before every timed call — zero it.
    hipMemsetAsync(d_out, 0, (size_t)out_size * sizeof(float), stream);

    const int block = 256;  // 4 waves/block, 4 edges/block

    {
        long long threads = (long long)EG * DDIM;
        unsigned grid = (unsigned)((threads + block - 1) / block);
        spmm_graph_kernel<<<grid, block, 0, stream>>>(
            g_rows, g_cols, g_vals, user_emb, item_emb, out, EG);
    }
    {
        long long threads = (long long)EU * DDIM;
        unsigned grid = (unsigned)((threads + block - 1) / block);
        spmm_plain_kernel<<<grid, block, 0, stream>>>(
            u_rows, u_cols, u_vals, user_emb,
            out + (size_t)N_CNT * DDIM, EU);
    }
    {
        long long threads = (long long)EI * DDIM;
        unsigned grid = (unsigned)((threads + block - 1) / block);
        spmm_plain_kernel<<<grid, block, 0, stream>>>(
            i_rows, i_cols, i_vals, item_emb,
            out + (size_t)N_CNT * DDIM + (size_t)U_CNT * DDIM, EI);
    }
}

// Round 2
// 916.128 us; speedup vs baseline: 1.3117x; 1.3117x over previous
//
#include <hip/hip_runtime.h>

#define DDIM 64
constexpr int U_CNT = 100000;
constexpr int I_CNT = 50000;
constexpr int N_CNT = U_CNT + I_CNT;          // 150000
constexpr int NB    = N_CNT + U_CNT + I_CNT;  // 300000 output rows / buckets
constexpr int SCAN_N = NB + 1;                // +1 sentinel for end offsets

// ---------------- wave-level scan helpers ----------------

__device__ __forceinline__ int wave_incl_scan(int v, int lane) {
#pragma unroll
    for (int off = 1; off < 64; off <<= 1) {
        int t = __shfl_up(v, off, 64);
        if (lane >= off) v += t;
    }
    return v;
}

// ---------------- counting-sort pipeline ----------------

// 1 thread per edge across all three matrices; bucket = output row id.
__global__ void hist_kernel(const int* __restrict__ gr, const int* __restrict__ ur,
                            const int* __restrict__ ir, int EG, int EU, int EI,
                            int* __restrict__ cnt) {
    int idx = blockIdx.x * blockDim.x + threadIdx.x;
    int b;
    if (idx < EG)                 b = gr[idx];
    else if (idx < EG + EU)       b = N_CNT + ur[idx - EG];
    else if (idx < EG + EU + EI)  b = N_CNT + U_CNT + ir[idx - EG - EU];
    else return;
    atomicAdd(&cnt[b], 1);
}

// Per-block partial sums over chunks of 1024 counters.
__global__ __launch_bounds__(1024) void scan_partials_kernel(const int* __restrict__ cnt,
                                                             int* __restrict__ partials, int n) {
    __shared__ int wsum[16];
    int tid = threadIdx.x, lane = tid & 63, wid = tid >> 6;
    int i = blockIdx.x * 1024 + tid;
    int v = (i < n) ? cnt[i] : 0;
#pragma unroll
    for (int m = 1; m < 64; m <<= 1) v += __shfl_xor(v, m, 64);
    if (lane == 0) wsum[wid] = v;
    __syncthreads();
    if (tid == 0) {
        int s = 0;
#pragma unroll
        for (int w = 0; w < 16; ++w) s += wsum[w];
        partials[blockIdx.x] = s;
    }
}

// Exclusive scan of the (<=1024) partials in place, single block.
__global__ __launch_bounds__(1024) void scan_block_kernel(int* __restrict__ partials, int np) {
    __shared__ int wsum[16];
    __shared__ int woff[16];
    int tid = threadIdx.x, lane = tid & 63, wid = tid >> 6;
    int v = (tid < np) ? partials[tid] : 0;
    int incl = wave_incl_scan(v, lane);
    if (lane == 63) wsum[wid] = incl;
    __syncthreads();
    if (wid == 0 && lane < 16) {
        int s = wsum[lane];
        int si = s;
#pragma unroll
        for (int off = 1; off < 16; off <<= 1) {
            int t = __shfl_up(si, off, 64);
            if (lane >= off) si += t;
        }
        woff[lane] = si - s;
    }
    __syncthreads();
    int excl = incl - v + woff[wid];
    if (tid < np) partials[tid] = excl;
}

// Final: block-local exclusive scan + scanned block base -> offs & cursor.
__global__ __launch_bounds__(1024) void scan_final_kernel(const int* __restrict__ cnt,
                                                          const int* __restrict__ partials,
                                                          int* __restrict__ offs,
                                                          int* __restrict__ cursor, int n) {
    __shared__ int wsum[16];
    __shared__ int woff[16];
    int tid = threadIdx.x, lane = tid & 63, wid = tid >> 6;
    int i = blockIdx.x * 1024 + tid;
    int v = (i < n) ? cnt[i] : 0;
    int incl = wave_incl_scan(v, lane);
    if (lane == 63) wsum[wid] = incl;
    __syncthreads();
    if (wid == 0 && lane < 16) {
        int s = wsum[lane];
        int si = s;
#pragma unroll
        for (int off = 1; off < 16; off <<= 1) {
            int t = __shfl_up(si, off, 64);
            if (lane >= off) si += t;
        }
        woff[lane] = si - s;
    }
    __syncthreads();
    int excl = incl - v + woff[wid] + partials[blockIdx.x];
    if (i < n) { offs[i] = excl; cursor[i] = excl; }
}

// Scatter (col, val) into pooled per-bucket segments.
__global__ void scatter_kernel(const int* __restrict__ gr, const int* __restrict__ gc,
                               const float* __restrict__ gv,
                               const int* __restrict__ ur, const int* __restrict__ uc,
                               const float* __restrict__ uv,
                               const int* __restrict__ ir, const int* __restrict__ ic,
                               const float* __restrict__ iv,
                               int EG, int EU, int EI,
                               int* __restrict__ cursor, int2* __restrict__ pool) {
    int idx = blockIdx.x * blockDim.x + threadIdx.x;
    int b, c; float v;
    if (idx < EG)                { b = gr[idx];                 c = gc[idx]; v = gv[idx]; }
    else if (idx < EG + EU)      { int j = idx - EG;            b = N_CNT + ur[j]; c = uc[j]; v = uv[j]; }
    else if (idx < EG + EU + EI) { int j = idx - EG - EU;       b = N_CNT + U_CNT + ir[j]; c = ic[j]; v = iv[j]; }
    else return;
    int pos = atomicAdd(&cursor[b], 1);
    pool[pos] = make_int2(c, __float_as_int(v));
}

// Atomic-free accumulate: one wave per output row, lane = feature dim.
__global__ void accum_kernel(const int* __restrict__ offs, const int2* __restrict__ pool,
                             const float* __restrict__ user_emb,
                             const float* __restrict__ item_emb,
                             float* __restrict__ out) {
    int lane = threadIdx.x & 63;
    int b = blockIdx.x * (blockDim.x >> 6) + (threadIdx.x >> 6);
    if (b >= NB) return;
    int start = offs[b], end = offs[b + 1];
    int seg = (b < N_CNT) ? 0 : (b < N_CNT + U_CNT ? 1 : 2);

    auto gather = [&](int c) -> float {
        if (seg == 0)
            return (c < U_CNT) ? user_emb[(size_t)c * DDIM + lane]
                               : item_emb[(size_t)(c - U_CNT) * DDIM + lane];
        if (seg == 1) return user_emb[(size_t)c * DDIM + lane];
        return item_emb[(size_t)c * DDIM + lane];
    };

    float acc = 0.f;
    int k = start;
    for (; k + 4 <= end; k += 4) {
        int2 p0 = pool[k], p1 = pool[k + 1], p2 = pool[k + 2], p3 = pool[k + 3];
        float x0 = gather(p0.x);
        float x1 = gather(p1.x);
        float x2 = gather(p2.x);
        float x3 = gather(p3.x);
        acc += __int_as_float(p0.y) * x0;
        acc += __int_as_float(p1.y) * x1;
        acc += __int_as_float(p2.y) * x2;
        acc += __int_as_float(p3.y) * x3;
    }
    for (; k < end; ++k) {
        int2 p = pool[k];
        acc += __int_as_float(p.y) * gather(p.x);
    }
    out[(size_t)b * DDIM + lane] = acc;
}

// ---------------- fallback (R1 atomic path) ----------------

__global__ void spmm_graph_kernel(const int* __restrict__ rows, const int* __restrict__ cols,
                                  const float* __restrict__ vals,
                                  const float* __restrict__ user_emb,
                                  const float* __restrict__ item_emb,
                                  float* __restrict__ out, int E) {
    long long idx = (long long)blockIdx.x * blockDim.x + threadIdx.x;
    int e = (int)(idx >> 6), d = (int)(idx & 63);
    if (e >= E) return;
    int r = rows[e], c = cols[e];
    float v = vals[e];
    float x = (c < U_CNT) ? user_emb[(long long)c * DDIM + d]
                          : item_emb[(long long)(c - U_CNT) * DDIM + d];
    atomicAdd(&out[(long long)r * DDIM + d], v * x);
}

__global__ void spmm_plain_kernel(const int* __restrict__ rows, const int* __restrict__ cols,
                                  const float* __restrict__ vals,
                                  const float* __restrict__ emb,
                                  float* __restrict__ out, int E) {
    long long idx = (long long)blockIdx.x * blockDim.x + threadIdx.x;
    int e = (int)(idx >> 6), d = (int)(idx & 63);
    if (e >= E) return;
    int r = rows[e], c = cols[e];
    float v = vals[e];
    float x = emb[(long long)c * DDIM + d];
    atomicAdd(&out[(long long)r * DDIM + d], v * x);
}

// ---------------- launch ----------------

extern "C" void kernel_launch(void* const* d_in, const int* in_sizes, int n_in,
                              void* d_out, int out_size, void* d_ws, size_t ws_size,
                              hipStream_t stream) {
    const float* user_emb = (const float*)d_in[0];
    const float* item_emb = (const float*)d_in[1];
    const int*   g_rows   = (const int*)d_in[2];
    const int*   g_cols   = (const int*)d_in[3];
    const float* g_vals   = (const float*)d_in[4];
    const int*   u_rows   = (const int*)d_in[5];
    const int*   u_cols   = (const int*)d_in[6];
    const float* u_vals   = (const float*)d_in[7];
    const int*   i_rows   = (const int*)d_in[8];
    const int*   i_cols   = (const int*)d_in[9];
    const float* i_vals   = (const float*)d_in[10];
    float* out = (float*)d_out;

    const int EG = in_sizes[2];
    const int EU = in_sizes[5];
    const int EI = in_sizes[8];
    const int E_total = EG + EU + EI;

    // Workspace layout: cnt[SCAN_N] | offs[SCAN_N] | cursor[SCAN_N] | pool[E_total] (int2)
    size_t ints_bytes = (size_t)3 * SCAN_N * sizeof(int);
    size_t pool_off   = (ints_bytes + 15) & ~(size_t)15;
    size_t needed     = pool_off + (size_t)E_total * sizeof(int2);

    if (ws_size >= needed) {
        int*  cnt    = (int*)d_ws;
        int*  offs   = cnt + SCAN_N;
        int*  cursor = offs + SCAN_N;
        int2* pool   = (int2*)((char*)d_ws + pool_off);

        hipMemsetAsync(cnt, 0, (size_t)SCAN_N * sizeof(int), stream);

        const int block = 256;
        unsigned egrid = (unsigned)((E_total + block - 1) / block);
        hist_kernel<<<egrid, block, 0, stream>>>(g_rows, u_rows, i_rows, EG, EU, EI, cnt);

        int nparts = (SCAN_N + 1023) / 1024;  // 294
        // reuse tail of cursor array region? partials need nparts ints — put after pool
        // (pool end) or just use offs buffer temporarily? partials must persist across
        // 3 kernels; allocate after pool:
        int* partials = (int*)((char*)d_ws + pool_off + (size_t)E_total * sizeof(int2));
        bool have_part_space = ws_size >= needed + (size_t)nparts * sizeof(int);
        if (!have_part_space) partials = cursor;  // safe: cursor written only in scan_final

        scan_partials_kernel<<<nparts, 1024, 0, stream>>>(cnt, partials, SCAN_N);
        scan_block_kernel<<<1, 1024, 0, stream>>>(partials, nparts);
        scan_final_kernel<<<nparts, 1024, 0, stream>>>(cnt, partials, offs, cursor, SCAN_N);

        scatter_kernel<<<egrid, block, 0, stream>>>(g_rows, g_cols, g_vals,
                                                    u_rows, u_cols, u_vals,
                                                    i_rows, i_cols, i_vals,
                                                    EG, EU, EI, cursor, pool);

        unsigned ablocks = (unsigned)((NB + 3) / 4);  // 4 waves (rows) per block
        accum_kernel<<<ablocks, 256, 0, stream>>>(offs, pool, user_emb, item_emb, out);
    } else {
        // Fallback: atomic scatter path (R1)
        hipMemsetAsync(d_out, 0, (size_t)out_size * sizeof(float), stream);
        const int block = 256;
        {
            long long threads = (long long)EG * DDIM;
            unsigned grid = (unsigned)((threads + block - 1) / block);
            spmm_graph_kernel<<<grid, block, 0, stream>>>(g_rows, g_cols, g_vals,
                                                          user_emb, item_emb, out, EG);
        }
        {
            long long threads = (long long)EU * DDIM;
            unsigned grid = (unsigned)((threads + block - 1) / block);
            spmm_plain_kernel<<<grid, block, 0, stream>>>(u_rows, u_cols, u_vals, user_emb,
                                                          out + (size_t)N_CNT * DDIM, EU);
        }
        {
            long long threads = (long long)EI * DDIM;
            unsigned grid = (unsigned)((threads + block - 1) / block);
            spmm_plain_kernel<<<grid, block, 0, stream>>>(i_rows, i_cols, i_vals, item_emb,
                                                          out + (size_t)(N_CNT + U_CNT) * DDIM, EI);
        }
    }
}